// Round 7
// baseline (584.054 us; speedup 1.0000x reference)
//
#include <hip/hip_runtime.h>
#include <math.h>

#define H 256
#define NB 2048
#define APG 64

typedef __attribute__((ext_vector_type(8))) short short8;
typedef __attribute__((ext_vector_type(4))) float f32x4;

__device__ __forceinline__ unsigned short f2bf(float f) {
    unsigned u = __float_as_uint(f);
    u += 0x7fff + ((u >> 16) & 1);   // RNE
    return (unsigned short)(u >> 16);
}
__device__ __forceinline__ float bf2f(unsigned short s) {
    return __uint_as_float((unsigned)s << 16);
}
__device__ __forceinline__ float sigm(float v) { return 1.f / (1.f + __expf(-v)); }

// ---------------- prep: Wr[hcol*4+gate][k] = bf16(W_ih+W_hh) ----------------
// Separate launch: every s2s block needs the FULL Wr, and correctness must not
// depend on co-residency/dispatch order (G16) — stream order guarantees it.
__global__ void prep_kernel(const float* __restrict__ W_ih, const float* __restrict__ W_hh,
                            unsigned short* __restrict__ Wr) {
    int idx = blockIdx.x * 256 + threadIdx.x;   // covers 1024*256 = 262144
    int wr_row = idx >> 8, k = idx & 255;
    int hcol = wr_row >> 2, gate = wr_row & 3;
    int src = gate * 65536 + hcol * 256 + k;
    Wr[idx] = f2bf(W_ih[src] + W_hh[src]);
}

// ---------------- single fused 3-step set2set: 1 block = 2 graphs -----------
// Zero cross-block deps: per-block LSTM (M=16-pad MFMA, 2 live rows, Wr
// streamed from L2) + per-graph attention with x re-staged from L3 each step
// (x fp32 = 128 MB < 256 MB Infinity Cache). LDS 39.3 KB -> 4 blocks/CU,
// 16 waves/CU; no persistent register arrays -> no spill surface.
__global__ __launch_bounds__(256)
void s2s(const float* __restrict__ x, const unsigned short* __restrict__ Wr,
         const float* __restrict__ b_ih, const float* __restrict__ b_hh,
         float* __restrict__ out) {
    __shared__ __align__(16) unsigned short xl[APG * H];   // 32 KB; gates overlay
    __shared__ __align__(16) float rpart[3][256];          // 3 KB
    __shared__ __align__(16) float qs[2][256];             // 2 KB
    __shared__ __align__(16) float q1s[256];               // 1 KB
    __shared__ __align__(16) unsigned short hb[2][H];      // 1 KB
    __shared__ __align__(16) float sc[64];                 // 0.25 KB
    float* gates = (float*)xl;                             // [2][1024] = 8 KB overlay

    int t = threadIdx.x;
    int lane = t & 63, w = t >> 6;
    int ln = lane & 15, qd = lane >> 4;
    int gbase = blockIdx.x * 2;

    // ---- prologue: biases (regs, thread t = hidden col t), analytic step-1 -
    float bi  = b_ih[t]       + b_hh[t];
    float bf_ = b_ih[256 + t] + b_hh[256 + t];
    float bg  = b_ih[512 + t] + b_hh[512 + t];
    float bo  = b_ih[768 + t] + b_hh[768 + t];
    float c1 = sigm(bi) * tanhf(bg);          // f-gate * c0 = 0
    q1s[t] = sigm(bo) * tanhf(c1);
    float cR0 = c1, cR1 = c1;                 // c-state in registers
    __syncthreads();

    for (int s = 0; s < 3; ++s) {
        if (s > 0) {
            // ---- LSTM: gates[16pad x 1024] = h @ Wr^T (R5-verified path) ---
            short8 a[8] = {};
            if (ln < 2) {
                #pragma unroll
                for (int kk = 0; kk < 8; ++kk)
                    a[kk] = *(short8*)&hb[ln][kk * 32 + qd * 8];
            }
            const unsigned short* wrow = Wr + (size_t)(w * 256 + ln) * H + qd * 8;
            #pragma unroll
            for (int tile = 0; tile < 16; ++tile) {
                const unsigned short* wt = wrow + (size_t)tile * 16 * H;
                f32x4 acc = {0.f, 0.f, 0.f, 0.f};
                #pragma unroll
                for (int kk = 0; kk < 8; ++kk) {
                    short8 b = *(const short8*)&wt[kk * 32];
                    acc = __builtin_amdgcn_mfma_f32_16x16x32_bf16(a[kk], b, acc, 0, 0, 0);
                }
                if (qd == 0) {   // C: row=(lane>>4)*4+reg, col=lane&15; rows 0,1 live
                    gates[0 * 1024 + w * 256 + tile * 16 + ln] = acc[0];
                    gates[1 * 1024 + w * 256 + tile * 16 + ln] = acc[1];
                }
            }
            __syncthreads();
            // ---- LSTM epilogue: thread t = hidden column ------------------
            #pragma unroll
            for (int j = 0; j < 2; ++j) {
                float4 g4 = *(float4*)&gates[j * 1024 + t * 4];
                float gi = g4.x + bi, gf = g4.y + bf_,
                      gg = g4.z + bg, go = g4.w + bo;
                float si = sigm(gi), sf = sigm(gf), so = sigm(go);
                float cprev = j ? cR1 : cR0;
                float cn = sf * cprev + si * tanhf(gg);
                if (j) cR1 = cn; else cR0 = cn;
                float qv = so * tanhf(cn);
                qs[j][t] = qv;
                if (s == 2) out[(size_t)(gbase + j) * 512 + t] = qv;
            }
            __syncthreads();   // gates dead after this; xl may be re-staged
        }

        // ---- attention: 2 graphs sequential; x re-staged from HBM/L3 ------
        for (int j = 0; j < 2; ++j) {
            const float* xg = x + (size_t)(gbase + j) * APG * H;
            float4 q4;
            if (s == 0) q4 = *(float4*)&q1s[lane * 4];
            else        q4 = *(float4*)&qs[j][lane * 4];
            // pass 1: stream fp32 x -> bf16 LDS, fp32 scores, wave-reduce
            #pragma unroll
            for (int i = 0; i < 16; ++i) {
                int row = i * 4 + w;
                float4 f = *(const float4*)&xg[row * H + lane * 4];
                ushort4 u;
                u.x = f2bf(f.x); u.y = f2bf(f.y); u.z = f2bf(f.z); u.w = f2bf(f.w);
                *(ushort4*)&xl[row * H + lane * 4] = u;
                float p = f.x * q4.x + f.y * q4.y + f.z * q4.z + f.w * q4.w;
                #pragma unroll
                for (int d = 32; d > 0; d >>= 1) p += __shfl_xor(p, d, 64);
                if (lane == 0) sc[row] = p;
            }
            __syncthreads();
            // softmax over 64 atom scores, redundant in all waves
            float sv = sc[lane], m = sv;
            #pragma unroll
            for (int d = 32; d > 0; d >>= 1) m = fmaxf(m, __shfl_xor(m, d, 64));
            float e = __expf(sv - m), sum = e;
            #pragma unroll
            for (int d = 32; d > 0; d >>= 1) sum += __shfl_xor(sum, d, 64);
            float pv = e / sum;   // lane holds prob of atom `lane`
            // pass 2: weighted sum from LDS bf16
            float4 r4 = {0.f, 0.f, 0.f, 0.f};
            #pragma unroll
            for (int i = 0; i < 16; ++i) {
                int row = i * 4 + w;
                float p = __shfl(pv, row, 64);
                ushort4 u = *(ushort4*)&xl[row * H + lane * 4];
                r4.x += p * bf2f(u.x); r4.y += p * bf2f(u.y);
                r4.z += p * bf2f(u.z); r4.w += p * bf2f(u.w);
            }
            if (w) *(float4*)&rpart[w - 1][lane * 4] = r4;
            __syncthreads();
            if (w == 0) {   // wave 0: final reduce, emit h (bf16) or r (fp32)
                float4 o4 = r4;
                #pragma unroll
                for (int k = 0; k < 3; ++k) {
                    float4 rr = *(float4*)&rpart[k][lane * 4];
                    o4.x += rr.x; o4.y += rr.y; o4.z += rr.z; o4.w += rr.w;
                }
                if (s < 2) {
                    ushort4 u;
                    u.x = f2bf(o4.x); u.y = f2bf(o4.y);
                    u.z = f2bf(o4.z); u.w = f2bf(o4.w);
                    *(ushort4*)&hb[j][lane * 4] = u;
                } else {
                    *(float4*)&out[(size_t)(gbase + j) * 512 + 256 + lane * 4] = o4;
                }
            }
            __syncthreads();   // xl free for next stage; hb stable for LSTM
        }
    }
}

extern "C" void kernel_launch(void* const* d_in, const int* in_sizes, int n_in,
                              void* d_out, int out_size, void* d_ws, size_t ws_size,
                              hipStream_t stream) {
    const float* x    = (const float*)d_in[0];
    // d_in[1]=batch, d_in[2]=sizes: deterministic (atom/64), unused.
    const float* W_ih = (const float*)d_in[3];
    const float* W_hh = (const float*)d_in[4];
    const float* b_ih = (const float*)d_in[5];
    const float* b_hh = (const float*)d_in[6];

    unsigned short* Wr = (unsigned short*)d_ws;          // 512 KB

    prep_kernel<<<1024, 256, 0, stream>>>(W_ih, W_hh, Wr);
    s2s<<<1024, 256, 0, stream>>>(x, Wr, b_ih, b_hh, (float*)d_out);
}

// Round 8
// 302.418 us; speedup vs baseline: 1.9313x; 1.9313x over previous
//
#include <hip/hip_runtime.h>
#include <math.h>

#define H 256
#define NB 2048
#define APG 64

typedef __attribute__((ext_vector_type(8))) short short8;
typedef __attribute__((ext_vector_type(4))) float f32x4;

__device__ __forceinline__ unsigned short f2bf(float f) {
    unsigned u = __float_as_uint(f);
    u += 0x7fff + ((u >> 16) & 1);   // RNE
    return (unsigned short)(u >> 16);
}
__device__ __forceinline__ float sigm(float v) { return 1.f / (1.f + __expf(-v)); }

// ---------------- prep: Wr = bf16(W_ih+W_hh); block 0 also does br/q1/c1 ----
// Wr[hcol*4+gate][k]; br[hc*4+gate]. Block 0's threads each own hidden col t:
// compute the 4 bias gates, the analytic step-1 LSTM (h=0, c=0) -> q1, c1.
__global__ void prep_kernel(const float* __restrict__ W_ih, const float* __restrict__ W_hh,
                            const float* __restrict__ b_ih, const float* __restrict__ b_hh,
                            unsigned short* __restrict__ Wr, float* __restrict__ br,
                            float* __restrict__ q1, float* __restrict__ c1) {
    int idx = blockIdx.x * 256 + threadIdx.x;   // covers 1024*256 = 262144
    int wr_row = idx >> 8, k = idx & 255;
    int hcol = wr_row >> 2, gate = wr_row & 3;
    int src = gate * 65536 + hcol * 256 + k;
    Wr[idx] = f2bf(W_ih[src] + W_hh[src]);
    if (blockIdx.x == 0) {
        int t = threadIdx.x;    // hidden column
        float bi  = b_ih[t]       + b_hh[t];
        float bf_ = b_ih[256 + t] + b_hh[256 + t];
        float bg  = b_ih[512 + t] + b_hh[512 + t];
        float bo  = b_ih[768 + t] + b_hh[768 + t];
        br[t * 4 + 0] = bi; br[t * 4 + 1] = bf_;
        br[t * 4 + 2] = bg; br[t * 4 + 3] = bo;
        float cn1 = sigm(bi) * tanhf(bg);      // f-gate * c0 = 0
        c1[t] = cn1;
        q1[t] = sigm(bo) * tanhf(cn1);
    }
}

// ---------------- fused MFMA GEMM + LSTM epilogue ---------------------------
// cin: row-stride cins (0 = broadcast c1 to every graph). cout nullable
// (step 3's cell state is dead).
__global__ __launch_bounds__(256)
void gemm_lstm(const unsigned short* __restrict__ hbf, const unsigned short* __restrict__ Wr,
               const float* __restrict__ br, const float* __restrict__ cin, int cins,
               float* __restrict__ cout, float* __restrict__ qdst, int qstride) {
    __shared__ unsigned short smem[2][64 * 128];
    unsigned short* As = smem[0];
    unsigned short* Bs = smem[1];
    int t = threadIdx.x;
    int r0 = blockIdx.y * 64;
    int w0 = blockIdx.x * 64;
    int c0h = blockIdx.x * 16;
    int lane = t & 63, w = t >> 6;
    int ln = lane & 15, qd = lane >> 4;
    int m0 = w * 16;
    f32x4 acc[4] = {};
    for (int kc = 0; kc < 2; ++kc) {
        #pragma unroll
        for (int p = 0; p < 4; ++p) {
            int gid = p * 256 + t;
            int row = gid >> 4, g = gid & 15;
            int sg = g ^ (row & 15);
            *(short8*)&As[row * 128 + sg * 8] =
                *(const short8*)&hbf[(r0 + row) * H + kc * 128 + g * 8];
            *(short8*)&Bs[row * 128 + sg * 8] =
                *(const short8*)&Wr[(w0 + row) * H + kc * 128 + g * 8];
        }
        __syncthreads();
        #pragma unroll
        for (int kk = 0; kk < 4; ++kk) {
            int ga = (kk * 4 + qd) ^ ln;
            short8 a = *(short8*)&As[(m0 + ln) * 128 + ga * 8];
            #pragma unroll
            for (int t4 = 0; t4 < 4; ++t4) {
                short8 b = *(short8*)&Bs[(t4 * 16 + ln) * 128 + ga * 8];
                acc[t4] = __builtin_amdgcn_mfma_f32_16x16x32_bf16(a, b, acc[t4], 0, 0, 0);
            }
        }
        __syncthreads();
    }
    float* gl = (float*)smem;
    #pragma unroll
    for (int t4 = 0; t4 < 4; ++t4)
        #pragma unroll
        for (int r = 0; r < 4; ++r)
            gl[(m0 + qd * 4 + r) * 68 + t4 * 16 + ln] = acc[t4][r];
    __syncthreads();
    #pragma unroll
    for (int p = 0; p < 4; ++p) {
        int idx = p * 256 + t;
        int row = idx >> 4, hc = idx & 15;
        float4 g4 = *(float4*)&gl[row * 68 + hc * 4];
        float4 b4 = *(const float4*)&br[(c0h + hc) * 4];
        float gi = g4.x + b4.x, gf = g4.y + b4.y, gg = g4.z + b4.z, go = g4.w + b4.w;
        float si = sigm(gi), sf = sigm(gf), so = sigm(go);
        float cprev = cin[(r0 + row) * cins + c0h + hc];
        float cn = sf * cprev + si * tanhf(gg);
        if (cout) cout[(r0 + row) * H + c0h + hc] = cn;
        qdst[(r0 + row) * qstride + c0h + hc] = so * tanhf(cn);
    }
}

// ---------------- attention: fp32 x, no LDS stage, pass-2 re-reads L2/L3 ----
// LDS 4.3 KB, low VGPR -> ~8 blocks/CU (32 waves/CU). One barrier between
// score pass and rpart phase; softmax computed redundantly in all 4 waves.
__global__ __launch_bounds__(256)
void attn(const float* __restrict__ x, const float* __restrict__ qsrc, int qstride,
          unsigned short* __restrict__ hbf_out, float* __restrict__ rout, int rstride) {
    __shared__ float sc[64];
    __shared__ __align__(16) float rpart[4][256];   // 4 KB
    int g = blockIdx.x, t = threadIdx.x;
    int lane = t & 63, w = t >> 6;
    const float* xg = x + (size_t)g * APG * H;

    float4 q4 = *(const float4*)&qsrc[(size_t)g * qstride + lane * 4];

    // pass 1: scores, wave-reduce (rows i*4+w; lane covers 4 features)
    #pragma unroll
    for (int i = 0; i < 16; ++i) {
        int row = i * 4 + w;
        float4 f = *(const float4*)&xg[row * H + lane * 4];
        float p = f.x * q4.x + f.y * q4.y + f.z * q4.z + f.w * q4.w;
        #pragma unroll
        for (int d = 32; d > 0; d >>= 1) p += __shfl_xor(p, d, 64);
        if (lane == 0) sc[row] = p;
    }
    __syncthreads();

    // softmax over 64 atom scores, redundant in every wave (no extra barrier)
    float sv = sc[lane], m = sv;
    #pragma unroll
    for (int d = 32; d > 0; d >>= 1) m = fmaxf(m, __shfl_xor(m, d, 64));
    float e = __expf(sv - m), sum = e;
    #pragma unroll
    for (int d = 32; d > 0; d >>= 1) sum += __shfl_xor(sum, d, 64);
    float pv = e / sum;   // lane holds prob of atom `lane`

    // pass 2: weighted sum; x re-read from global (L2/L3-hot after pass 1)
    float4 r4 = {0.f, 0.f, 0.f, 0.f};
    #pragma unroll
    for (int i = 0; i < 16; ++i) {
        int row = i * 4 + w;
        float p = __shfl(pv, row, 64);
        float4 f = *(const float4*)&xg[row * H + lane * 4];
        r4.x += p * f.x; r4.y += p * f.y; r4.z += p * f.z; r4.w += p * f.w;
    }
    *(float4*)&rpart[w][lane * 4] = r4;
    __syncthreads();
    float o = rpart[0][t] + rpart[1][t] + rpart[2][t] + rpart[3][t];
    if (hbf_out) hbf_out[(size_t)g * H + t] = f2bf(o);
    if (rout)    rout[(size_t)g * rstride + t] = o;
}

extern "C" void kernel_launch(void* const* d_in, const int* in_sizes, int n_in,
                              void* d_out, int out_size, void* d_ws, size_t ws_size,
                              hipStream_t stream) {
    const float* x    = (const float*)d_in[0];
    // d_in[1]=batch, d_in[2]=sizes: deterministic (atom/64), unused.
    const float* W_ih = (const float*)d_in[3];
    const float* W_hh = (const float*)d_in[4];
    const float* b_ih = (const float*)d_in[5];
    const float* b_hh = (const float*)d_in[6];
    float* out = (float*)d_out;

    char* ws = (char*)d_ws;
    unsigned short* Wr   = (unsigned short*)ws;             // 512 KB
    float*          br   = (float*)(ws + 524288);           // 4 KB
    float*          q1   = (float*)(ws + 528384);           // 1 KB
    float*          c1   = (float*)(ws + 529408);           // 1 KB
    float*          cbuf = (float*)(ws + 532480);           // 2 MB
    float*          qbuf = (float*)(ws + 2629632);          // 2 MB
    unsigned short* hbf  = (unsigned short*)(ws + 4726784); // 1 MB

    prep_kernel<<<1024, 256, 0, stream>>>(W_ih, W_hh, b_ih, b_hh, Wr, br, q1, c1);
    // step 1: q1 broadcast (qstride=0) -> hbf
    attn<<<2048, 256, 0, stream>>>(x, q1, 0, hbf, nullptr, 0);
    // step 2: c-in broadcast from c1 (stride 0)
    gemm_lstm<<<dim3(16, 32), 256, 0, stream>>>(hbf, Wr, br, c1, 0, cbuf, qbuf, 256);
    attn<<<2048, 256, 0, stream>>>(x, qbuf, 256, hbf, nullptr, 0);
    // step 3: q into out[:, :256]; cell state dead (cout = nullptr)
    gemm_lstm<<<dim3(16, 32), 256, 0, stream>>>(hbf, Wr, br, cbuf, 256, nullptr, out, 512);
    attn<<<2048, 256, 0, stream>>>(x, out, 512, nullptr, out + 256, 512);
}

// Round 9
// 264.272 us; speedup vs baseline: 2.2100x; 1.1443x over previous
//
#include <hip/hip_runtime.h>
#include <math.h>

#define H 256
#define NB 2048
#define APG 64

typedef __attribute__((ext_vector_type(8))) short short8;
typedef __attribute__((ext_vector_type(4))) float f32x4;

__device__ __forceinline__ unsigned short f2bf(float f) {
    unsigned u = __float_as_uint(f);
    u += 0x7fff + ((u >> 16) & 1);   // RNE
    return (unsigned short)(u >> 16);
}
__device__ __forceinline__ float sigm(float v) { return 1.f / (1.f + __expf(-v)); }

// ---------------- fused MFMA GEMM + LSTM epilogue (R8-verified) -------------
// cin: row-stride cins (0 = broadcast c1 to every graph). cout nullable.
__global__ __launch_bounds__(256)
void gemm_lstm(const unsigned short* __restrict__ hbf, const unsigned short* __restrict__ Wr,
               const float* __restrict__ br, const float* __restrict__ cin, int cins,
               float* __restrict__ cout, float* __restrict__ qdst, int qstride) {
    __shared__ unsigned short smem[2][64 * 128];
    unsigned short* As = smem[0];
    unsigned short* Bs = smem[1];
    int t = threadIdx.x;
    int r0 = blockIdx.y * 64;
    int w0 = blockIdx.x * 64;
    int c0h = blockIdx.x * 16;
    int lane = t & 63, w = t >> 6;
    int ln = lane & 15, qd = lane >> 4;
    int m0 = w * 16;
    f32x4 acc[4] = {};
    for (int kc = 0; kc < 2; ++kc) {
        #pragma unroll
        for (int p = 0; p < 4; ++p) {
            int gid = p * 256 + t;
            int row = gid >> 4, g = gid & 15;
            int sg = g ^ (row & 15);
            *(short8*)&As[row * 128 + sg * 8] =
                *(const short8*)&hbf[(r0 + row) * H + kc * 128 + g * 8];
            *(short8*)&Bs[row * 128 + sg * 8] =
                *(const short8*)&Wr[(w0 + row) * H + kc * 128 + g * 8];
        }
        __syncthreads();
        #pragma unroll
        for (int kk = 0; kk < 4; ++kk) {
            int ga = (kk * 4 + qd) ^ ln;
            short8 a = *(short8*)&As[(m0 + ln) * 128 + ga * 8];
            #pragma unroll
            for (int t4 = 0; t4 < 4; ++t4) {
                short8 b = *(short8*)&Bs[(t4 * 16 + ln) * 128 + ga * 8];
                acc[t4] = __builtin_amdgcn_mfma_f32_16x16x32_bf16(a, b, acc[t4], 0, 0, 0);
            }
        }
        __syncthreads();
    }
    float* gl = (float*)smem;
    #pragma unroll
    for (int t4 = 0; t4 < 4; ++t4)
        #pragma unroll
        for (int r = 0; r < 4; ++r)
            gl[(m0 + qd * 4 + r) * 68 + t4 * 16 + ln] = acc[t4][r];
    __syncthreads();
    #pragma unroll
    for (int p = 0; p < 4; ++p) {
        int idx = p * 256 + t;
        int row = idx >> 4, hc = idx & 15;
        float4 g4 = *(float4*)&gl[row * 68 + hc * 4];
        float4 b4 = *(const float4*)&br[(c0h + hc) * 4];
        float gi = g4.x + b4.x, gf = g4.y + b4.y, gg = g4.z + b4.z, go = g4.w + b4.w;
        float si = sigm(gi), sf = sigm(gf), so = sigm(go);
        float cprev = cin[(r0 + row) * cins + c0h + hc];
        float cn = sf * cprev + si * tanhf(gg);
        if (cout) cout[(r0 + row) * H + c0h + hc] = cn;
        qdst[(r0 + row) * qstride + c0h + hc] = so * tanhf(cn);
    }
}

// ---------------- attention step 1 + folded prep/lstm0 ----------------------
// x fp32 in registers (R0-proven pattern). Each block computes q1 from biases
// (LDS q1s); each block converts a 128-elem strip of Wr; block 0 writes br/c1.
// One barrier between score pass and rpart phase (softmax redundant per wave).
__global__ __launch_bounds__(256)
void attn1(const float* __restrict__ x,
           const float* __restrict__ W_ih, const float* __restrict__ W_hh,
           const float* __restrict__ b_ih, const float* __restrict__ b_hh,
           unsigned short* __restrict__ Wr, float* __restrict__ br,
           float* __restrict__ c1, unsigned short* __restrict__ hbf_out) {
    __shared__ float q1s[256];
    __shared__ float sc[64];
    __shared__ __align__(16) float rpart[4][256];
    int g = blockIdx.x, t = threadIdx.x;
    int lane = t & 63, w = t >> 6;
    const float* xg = x + (size_t)g * APG * H;

    // x -> fp32 registers (kernel-lifetime only; no persistence across phases)
    float4 xa[16];
    #pragma unroll
    for (int i = 0; i < 16; ++i)
        xa[i] = *(const float4*)&xg[(i * 4 + w) * H + lane * 4];

    // folded prep: q1 per block; br/c1 by block 0; Wr strip per block
    {
        float bi  = b_ih[t]       + b_hh[t];
        float bf_ = b_ih[256 + t] + b_hh[256 + t];
        float bg  = b_ih[512 + t] + b_hh[512 + t];
        float bo  = b_ih[768 + t] + b_hh[768 + t];
        float cn1 = sigm(bi) * tanhf(bg);      // f-gate * c0 = 0
        q1s[t] = sigm(bo) * tanhf(cn1);
        if (g == 0) {
            br[t * 4 + 0] = bi; br[t * 4 + 1] = bf_;
            br[t * 4 + 2] = bg; br[t * 4 + 3] = bo;
            c1[t] = cn1;
        }
        if (t < 128) {                         // 2048 blocks x 128 = 262144
            int idx = g * 128 + t;
            int wr_row = idx >> 8, k = idx & 255;
            int hcol = wr_row >> 2, gate = wr_row & 3;
            int src = gate * 65536 + hcol * 256 + k;
            Wr[idx] = f2bf(W_ih[src] + W_hh[src]);
        }
    }
    __syncthreads();
    float4 q4 = *(float4*)&q1s[lane * 4];

    // pass 1: scores, wave-reduce
    #pragma unroll
    for (int i = 0; i < 16; ++i) {
        float p = xa[i].x * q4.x + xa[i].y * q4.y + xa[i].z * q4.z + xa[i].w * q4.w;
        #pragma unroll
        for (int d = 32; d > 0; d >>= 1) p += __shfl_xor(p, d, 64);
        if (lane == 0) sc[i * 4 + w] = p;
    }
    __syncthreads();

    // softmax over 64 atom scores, redundant in every wave
    float sv = sc[lane], m = sv;
    #pragma unroll
    for (int d = 32; d > 0; d >>= 1) m = fmaxf(m, __shfl_xor(m, d, 64));
    float e = __expf(sv - m), sum = e;
    #pragma unroll
    for (int d = 32; d > 0; d >>= 1) sum += __shfl_xor(sum, d, 64);
    float pv = e / sum;   // lane holds prob of atom `lane`

    // pass 2: weighted sum from registers
    float4 r4 = {0.f, 0.f, 0.f, 0.f};
    #pragma unroll
    for (int i = 0; i < 16; ++i) {
        float p = __shfl(pv, i * 4 + w, 64);
        r4.x += p * xa[i].x; r4.y += p * xa[i].y;
        r4.z += p * xa[i].z; r4.w += p * xa[i].w;
    }
    *(float4*)&rpart[w][lane * 4] = r4;
    __syncthreads();
    float o = rpart[0][t] + rpart[1][t] + rpart[2][t] + rpart[3][t];
    hbf_out[(size_t)g * H + t] = f2bf(o);
}

// ---------------- attention steps 2-3: same core, q from qsrc ---------------
__global__ __launch_bounds__(256)
void attn23(const float* __restrict__ x, const float* __restrict__ qsrc, int qstride,
            unsigned short* __restrict__ hbf_out, float* __restrict__ rout, int rstride) {
    __shared__ float sc[64];
    __shared__ __align__(16) float rpart[4][256];
    int g = blockIdx.x, t = threadIdx.x;
    int lane = t & 63, w = t >> 6;
    const float* xg = x + (size_t)g * APG * H;

    float4 xa[16];
    #pragma unroll
    for (int i = 0; i < 16; ++i)
        xa[i] = *(const float4*)&xg[(i * 4 + w) * H + lane * 4];
    float4 q4 = *(const float4*)&qsrc[(size_t)g * qstride + lane * 4];

    #pragma unroll
    for (int i = 0; i < 16; ++i) {
        float p = xa[i].x * q4.x + xa[i].y * q4.y + xa[i].z * q4.z + xa[i].w * q4.w;
        #pragma unroll
        for (int d = 32; d > 0; d >>= 1) p += __shfl_xor(p, d, 64);
        if (lane == 0) sc[i * 4 + w] = p;
    }
    __syncthreads();

    float sv = sc[lane], m = sv;
    #pragma unroll
    for (int d = 32; d > 0; d >>= 1) m = fmaxf(m, __shfl_xor(m, d, 64));
    float e = __expf(sv - m), sum = e;
    #pragma unroll
    for (int d = 32; d > 0; d >>= 1) sum += __shfl_xor(sum, d, 64);
    float pv = e / sum;

    float4 r4 = {0.f, 0.f, 0.f, 0.f};
    #pragma unroll
    for (int i = 0; i < 16; ++i) {
        float p = __shfl(pv, i * 4 + w, 64);
        r4.x += p * xa[i].x; r4.y += p * xa[i].y;
        r4.z += p * xa[i].z; r4.w += p * xa[i].w;
    }
    *(float4*)&rpart[w][lane * 4] = r4;
    __syncthreads();
    float o = rpart[0][t] + rpart[1][t] + rpart[2][t] + rpart[3][t];
    if (hbf_out) hbf_out[(size_t)g * H + t] = f2bf(o);
    if (rout)    rout[(size_t)g * rstride + t] = o;
}

extern "C" void kernel_launch(void* const* d_in, const int* in_sizes, int n_in,
                              void* d_out, int out_size, void* d_ws, size_t ws_size,
                              hipStream_t stream) {
    const float* x    = (const float*)d_in[0];
    // d_in[1]=batch, d_in[2]=sizes: deterministic (atom/64), unused.
    const float* W_ih = (const float*)d_in[3];
    const float* W_hh = (const float*)d_in[4];
    const float* b_ih = (const float*)d_in[5];
    const float* b_hh = (const float*)d_in[6];
    float* out = (float*)d_out;

    char* ws = (char*)d_ws;
    unsigned short* Wr   = (unsigned short*)ws;             // 512 KB
    float*          br   = (float*)(ws + 524288);           // 4 KB
    float*          c1   = (float*)(ws + 528384);           // 1 KB
    float*          cbuf = (float*)(ws + 532480);           // 2 MB
    float*          qbuf = (float*)(ws + 2629632);          // 2 MB
    unsigned short* hbf  = (unsigned short*)(ws + 4726784); // 1 MB

    // step 1: attention with folded prep/lstm0 (writes hbf, Wr, br, c1)
    attn1<<<2048, 256, 0, stream>>>(x, W_ih, W_hh, b_ih, b_hh, Wr, br, c1, hbf);
    // step 2: c-in broadcast from c1 (stride 0)
    gemm_lstm<<<dim3(16, 32), 256, 0, stream>>>(hbf, Wr, br, c1, 0, cbuf, qbuf, 256);
    attn23<<<2048, 256, 0, stream>>>(x, qbuf, 256, hbf, nullptr, 0);
    // step 3: q into out[:, :256]; cell state dead (cout = nullptr)
    gemm_lstm<<<dim3(16, 32), 256, 0, stream>>>(hbf, Wr, br, cbuf, 256, nullptr, out, 512);
    attn23<<<2048, 256, 0, stream>>>(x, out, 512, nullptr, out + 256, 512);
}